// Round 2
// baseline (587.411 us; speedup 1.0000x reference)
//
#include <hip/hip_runtime.h>
#include <math.h>

#define NN 262144
#define DD 256

typedef __attribute__((ext_vector_type(8))) short bf16x8;   // 8 bf16 = 4 VGPRs
typedef __attribute__((ext_vector_type(4))) float f32x4;

#define MFMA __builtin_amdgcn_mfma_f32_16x16x32_bf16

union U8 { bf16x8 v; unsigned int u[4]; };

// 16B-chunk XOR swizzle on fp32 [64][256] tile: conflict-free b128 access
__device__ __forceinline__ int swzf(int row, int k) {
  return (row << 8) + ((((k >> 2) ^ (row & 7)) << 2) | (k & 3));
}

// exact 3-way truncation split of a pair of fp32 -> packed bf16 pairs.
// a = hi + mid + lo exactly (up to 1 ulp of fp32 in lo's last bit).
__device__ __forceinline__ void split2(float a0, float a1,
                                       unsigned int& ph, unsigned int& pm, unsigned int& pl) {
  unsigned int u0 = __float_as_uint(a0), u1 = __float_as_uint(a1);
  ph = __builtin_amdgcn_perm(u1, u0, 0x07060302u);      // [bf(a1)|bf(a0)] trunc
  float h0 = __uint_as_float(u0 & 0xffff0000u);
  float h1 = __uint_as_float(u1 & 0xffff0000u);
  float r0 = a0 - h0, r1 = a1 - h1;                     // exact
  unsigned int v0 = __float_as_uint(r0), v1 = __float_as_uint(r1);
  pm = __builtin_amdgcn_perm(v1, v0, 0x07060302u);
  float m0 = __uint_as_float(v0 & 0xffff0000u);
  float m1 = __uint_as_float(v1 & 0xffff0000u);
  float s0 = r0 - m0, s1 = r1 - m1;                     // exact
  pl = __builtin_amdgcn_perm(__float_as_uint(s1), __float_as_uint(s0), 0x07060302u);
}

// ---------------- prep: exact 3-way trunc split of W1 -----------------------
__global__ void prep_kernel(const float* __restrict__ W1,
                            unsigned short* __restrict__ wa,
                            unsigned short* __restrict__ wb,
                            unsigned short* __restrict__ wc) {
  int t = blockIdx.x * 256 + threadIdx.x;
  float v = W1[t];
  unsigned int uv = __float_as_uint(v);
  float hi = __uint_as_float(uv & 0xffff0000u);
  float r1 = v - hi;
  unsigned int u1 = __float_as_uint(r1);
  float mi = __uint_as_float(u1 & 0xffff0000u);
  float r2 = r1 - mi;
  unsigned int u2 = __float_as_uint(r2);
  wa[t] = (unsigned short)(uv >> 16);
  wb[t] = (unsigned short)(u1 >> 16);
  wc[t] = (unsigned short)(u2 >> 16);
}

// ---------------- fused MLP: gelu(A@W1^T+b1)@W2^T + b2 -> M [N][9] ----------
__global__ __launch_bounds__(256, 2) void mlp_kernel(
    const float* __restrict__ A, const float* __restrict__ b1,
    const float* __restrict__ b2, const float* __restrict__ W2,
    const unsigned short* __restrict__ w1a, const unsigned short* __restrict__ w1b,
    const unsigned short* __restrict__ w1c, float* __restrict__ Mout)
{
  __shared__ float sA[64 * 256];        // 64 KB: A tile fp32, later h fp32
  __shared__ float sMp[4 * 64 * 12];    // 12 KB: GEMM2 cross-wave partials
  const int tid  = threadIdx.x;
  const int lane = tid & 63;
  const int wv   = tid >> 6;            // wave 0..3 -> 64-col strip of W1
  const int n0   = blockIdx.x * 64;

  // ---- stage A tile [64][256] fp32 -> LDS (swizzled), one barrier total ----
  const float4* A4 = (const float4*)(A + (size_t)n0 * DD);
  #pragma unroll
  for (int it = 0; it < 16; ++it) {
    int f   = (it << 8) + tid;          // 0..4095 float4s
    int row = f >> 6;
    int kc  = (f & 63) << 2;
    float4 v = A4[f];
    *(float4*)&sA[swzf(row, kc)] = v;
  }
  __syncthreads();

  const int m  = lane & 15;
  const int g  = lane >> 4;
  const int kq = g << 3;

  f32x4 acc[4][4];
  #pragma unroll
  for (int r = 0; r < 4; ++r)
    #pragma unroll
    for (int c = 0; c < 4; ++c)
      acc[r][c] = (f32x4){0.f, 0.f, 0.f, 0.f};

  int boff[4];
  #pragma unroll
  for (int c = 0; c < 4; ++c) boff[c] = (wv * 64 + c * 16 + m) * DD + kq;

  #pragma unroll
  for (int ks = 0; ks < 8; ++ks) {
    // B fragments: 3 levels x 4 cols from L2 (W1 pre-split, 384 KB resident)
    bf16x8 Ba[4], Bb[4], Bc[4];
    #pragma unroll
    for (int c = 0; c < 4; ++c) {
      Ba[c] = *(const bf16x8*)(w1a + boff[c] + ks * 32);
      Bb[c] = *(const bf16x8*)(w1b + boff[c] + ks * 32);
      Bc[c] = *(const bf16x8*)(w1c + boff[c] + ks * 32);
    }
    // A fragments: fp32 from LDS, exact 3-way split on the fly
    U8 Aa[4], Ab[4], Ac[4];
    #pragma unroll
    for (int r = 0; r < 4; ++r) {
      int row = r * 16 + m;
      int k0  = ks * 32 + kq;
      float4 p = *(const float4*)&sA[swzf(row, k0)];
      float4 q = *(const float4*)&sA[swzf(row, k0 + 4)];
      split2(p.x, p.y, Aa[r].u[0], Ab[r].u[0], Ac[r].u[0]);
      split2(p.z, p.w, Aa[r].u[1], Ab[r].u[1], Ac[r].u[1]);
      split2(q.x, q.y, Aa[r].u[2], Ab[r].u[2], Ac[r].u[2]);
      split2(q.z, q.w, Aa[r].u[3], Ab[r].u[3], Ac[r].u[3]);
    }
    // 6-product emulated-fp32 MFMA (small terms first)
    #pragma unroll
    for (int r = 0; r < 4; ++r)
      #pragma unroll
      for (int c = 0; c < 4; ++c) {
        f32x4 t;
        t = MFMA(Ac[r].v, Ba[c], acc[r][c], 0, 0, 0);
        t = MFMA(Ab[r].v, Bb[c], t, 0, 0, 0);
        t = MFMA(Aa[r].v, Bc[c], t, 0, 0, 0);
        t = MFMA(Ab[r].v, Ba[c], t, 0, 0, 0);
        t = MFMA(Aa[r].v, Bb[c], t, 0, 0, 0);
        acc[r][c] = MFMA(Aa[r].v, Ba[c], t, 0, 0, 0);
      }
  }
  __syncthreads();   // everyone done reading A before h overwrites LDS

  // ---- epilogue: +b1, exact-erf GELU (fp32), h fp32 -> LDS ----
  const int rowq = g << 2;
  #pragma unroll
  for (int c = 0; c < 4; ++c) {
    int j = wv * 64 + c * 16 + m;
    float bias = b1[j];
    #pragma unroll
    for (int r = 0; r < 4; ++r) {
      #pragma unroll
      for (int ri = 0; ri < 4; ++ri) {
        float x  = acc[r][c][ri] + bias;
        float gl = 0.5f * x * (1.f + erff(x * 0.70710678118654752f));
        sA[swzf(r * 16 + rowq + ri, j)] = gl;
      }
    }
  }
  __syncthreads();

  // ---- GEMM2 fp32 VALU: wave wv handles K-range [wv*64, wv*64+64), row=lane
  float accj[9];
  #pragma unroll
  for (int j = 0; j < 9; ++j) accj[j] = 0.f;
  int kbase = __builtin_amdgcn_readfirstlane(wv << 6);   // wave-uniform -> s_loads
  const float* w2k = W2 + kbase;
  #pragma unroll
  for (int kk = 0; kk < 64; kk += 4) {
    float4 h4 = *(const float4*)&sA[swzf(lane, kbase + kk)];
    #pragma unroll
    for (int j = 0; j < 9; ++j) {
      const float* wj = w2k + j * DD + kk;
      accj[j] = fmaf(h4.x, wj[0],
                fmaf(h4.y, wj[1],
                fmaf(h4.z, wj[2],
                fmaf(h4.w, wj[3], accj[j]))));
    }
  }
  #pragma unroll
  for (int j = 0; j < 9; ++j) sMp[(wv * 64 + lane) * 12 + j] = accj[j];
  __syncthreads();

  for (int o = tid; o < 576; o += 256) {
    int row = o / 9, j = o - row * 9;
    float s = sMp[(row) * 12 + j] + sMp[(64 + row) * 12 + j] +
              sMp[(128 + row) * 12 + j] + sMp[(192 + row) * 12 + j] + b2[j];
    Mout[(size_t)(n0 + row) * 9 + j] = s;
  }
}

// ---------------- procrustes: Horn quaternion, fp32 Jacobi + fp64 refine ----
template <int P, int Q>
__device__ __forceinline__ void jrot(float Aq[4][4], float V[4][4]) {
  float apq = Aq[P][Q];
  float d   = Aq[Q][Q] - Aq[P][P];
  float sq  = sqrtf(d * d + 4.f * apq * apq);
  float den = fmaxf(fabsf(d) + sq, 1e-35f);
  float tt  = 2.f * apq * copysignf(1.f, d) / den;
  float c   = rsqrtf(1.f + tt * tt);
  float s   = tt * c;
  float app = Aq[P][P], aqq = Aq[Q][Q];
  Aq[P][P] = app - tt * apq;
  Aq[Q][Q] = aqq + tt * apq;
  Aq[P][Q] = 0.f; Aq[Q][P] = 0.f;
  #pragma unroll
  for (int r = 0; r < 4; ++r) {
    if (r == P || r == Q) continue;
    float arp = Aq[r][P], arq = Aq[r][Q];
    Aq[r][P] = Aq[P][r] = c * arp - s * arq;
    Aq[r][Q] = Aq[Q][r] = s * arp + c * arq;
  }
  #pragma unroll
  for (int i = 0; i < 4; ++i) {
    float vp = V[i][P], vq = V[i][Q];
    V[i][P] = c * vp - s * vq;
    V[i][Q] = s * vp + c * vq;
  }
}

__device__ __forceinline__ double det3(double a, double b, double c,
                                       double d, double e, double f,
                                       double g, double h, double i) {
  return a * (e * i - f * h) - b * (d * i - f * g) + c * (d * h - e * g);
}

__global__ __launch_bounds__(256) void procrustes_kernel(const float* __restrict__ M,
                                                         float* __restrict__ out) {
  int t = blockIdx.x * 256 + threadIdx.x;
  const float* mp = M + (size_t)t * 9;
  float m00 = mp[0], m01 = mp[1], m02 = mp[2];
  float m10 = mp[3], m11 = mp[4], m12 = mp[5];
  float m20 = mp[6], m21 = mp[7], m22 = mp[8];

  // Horn N(M): max eigvec == special procrustes rotation (as quaternion)
  float Aq[4][4], V[4][4];
  Aq[0][0] =  m00 + m11 + m22;
  Aq[1][1] =  m00 - m11 - m22;
  Aq[2][2] = -m00 + m11 - m22;
  Aq[3][3] = -m00 - m11 + m22;
  Aq[0][1] = Aq[1][0] = m21 - m12;
  Aq[0][2] = Aq[2][0] = m02 - m20;
  Aq[0][3] = Aq[3][0] = m10 - m01;
  Aq[1][2] = Aq[2][1] = m01 + m10;
  Aq[1][3] = Aq[3][1] = m02 + m20;
  Aq[2][3] = Aq[3][2] = m12 + m21;
  #pragma unroll
  for (int i = 0; i < 4; ++i)
    #pragma unroll
    for (int j = 0; j < 4; ++j)
      V[i][j] = (i == j) ? 1.f : 0.f;

  #pragma unroll
  for (int sweep = 0; sweep < 5; ++sweep) {
    jrot<0,1>(Aq, V); jrot<0,2>(Aq, V); jrot<0,3>(Aq, V);
    jrot<1,2>(Aq, V); jrot<1,3>(Aq, V); jrot<2,3>(Aq, V);
  }

  float bv = Aq[0][0];
  float qw = V[0][0], qx = V[1][0], qy = V[2][0], qz = V[3][0];
  #define PICK(K) if (Aq[K][K] > bv) { bv = Aq[K][K]; qw = V[0][K]; qx = V[1][K]; qy = V[2][K]; qz = V[3][K]; }
  PICK(1) PICK(2) PICK(3)
  #undef PICK

  // ---- fp64 refinement: one Rayleigh-shifted adjugate inverse-iteration ----
  double d00 = (double)m00, d01 = (double)m01, d02 = (double)m02;
  double d10 = (double)m10, d11 = (double)m11, d12 = (double)m12;
  double d20 = (double)m20, d21 = (double)m21, d22 = (double)m22;
  double Nd[4][4];
  Nd[0][0] =  d00 + d11 + d22;
  Nd[1][1] =  d00 - d11 - d22;
  Nd[2][2] = -d00 + d11 - d22;
  Nd[3][3] = -d00 - d11 + d22;
  Nd[0][1] = Nd[1][0] = d21 - d12;
  Nd[0][2] = Nd[2][0] = d02 - d20;
  Nd[0][3] = Nd[3][0] = d10 - d01;
  Nd[1][2] = Nd[2][1] = d01 + d10;
  Nd[1][3] = Nd[3][1] = d02 + d20;
  Nd[2][3] = Nd[3][2] = d12 + d21;

  double qd[4] = {(double)qw, (double)qx, (double)qy, (double)qz};
  double nn = qd[0]*qd[0] + qd[1]*qd[1] + qd[2]*qd[2] + qd[3]*qd[3];
  double Nq[4];
  #pragma unroll
  for (int i = 0; i < 4; ++i)
    Nq[i] = Nd[i][0]*qd[0] + Nd[i][1]*qd[1] + Nd[i][2]*qd[2] + Nd[i][3]*qd[3];
  double sig = (qd[0]*Nq[0] + qd[1]*Nq[1] + qd[2]*Nq[2] + qd[3]*Nq[3]) / nn;

  double Ad[4][4];
  #pragma unroll
  for (int i = 0; i < 4; ++i)
    #pragma unroll
    for (int j = 0; j < 4; ++j)
      Ad[i][j] = Nd[i][j] - (i == j ? sig : 0.0);

  // y = adj(A) * q  (A symmetric => adj[i][j] = (-1)^{i+j} minor(i,j))
  double y[4];
  #pragma unroll
  for (int i = 0; i < 4; ++i) {
    double yi = 0.0;
    #pragma unroll
    for (int j = 0; j < 4; ++j) {
      const int r0 = (i == 0) ? 1 : 0, r1 = (i <= 1) ? 2 : 1, r2 = (i <= 2) ? 3 : 2;
      const int c0 = (j == 0) ? 1 : 0, c1 = (j <= 1) ? 2 : 1, c2 = (j <= 2) ? 3 : 2;
      double mnr = det3(Ad[r0][c0], Ad[r0][c1], Ad[r0][c2],
                        Ad[r1][c0], Ad[r1][c1], Ad[r1][c2],
                        Ad[r2][c0], Ad[r2][c1], Ad[r2][c2]);
      double s = ((i + j) & 1) ? -mnr : mnr;
      yi += s * qd[j];
    }
    y[i] = yi;
  }
  double yn = y[0]*y[0] + y[1]*y[1] + y[2]*y[2] + y[3]*y[3];
  if (!(yn > 1e-280)) { y[0] = qd[0]; y[1] = qd[1]; y[2] = qd[2]; y[3] = qd[3]; yn = nn; }
  double inv = 1.0 / sqrt(yn);
  double w = y[0]*inv, x = y[1]*inv, yv = y[2]*inv, z = y[3]*inv;

  double xx = x*x, yy = yv*yv, zz = z*z;
  double xy = x*yv, xz = x*z, yz = yv*z;
  double wx = w*x, wy = w*yv, wz = w*z;

  float* op = out + (size_t)t * 9;
  op[0] = (float)(1.0 - 2.0*(yy + zz));
  op[1] = (float)(2.0*(xy - wz));
  op[2] = (float)(2.0*(xz + wy));
  op[3] = (float)(2.0*(xy + wz));
  op[4] = (float)(1.0 - 2.0*(xx + zz));
  op[5] = (float)(2.0*(yz - wx));
  op[6] = (float)(2.0*(xz - wy));
  op[7] = (float)(2.0*(yz + wx));
  op[8] = (float)(1.0 - 2.0*(xx + yy));
}

extern "C" void kernel_launch(void* const* d_in, const int* in_sizes, int n_in,
                              void* d_out, int out_size, void* d_ws, size_t ws_size,
                              hipStream_t stream) {
  const float* bb = (const float*)d_in[0];
  const float* W1 = (const float*)d_in[1];
  const float* b1 = (const float*)d_in[2];
  const float* W2 = (const float*)d_in[3];
  const float* b2 = (const float*)d_in[4];
  float* out = (float*)d_out;
  char* ws = (char*)d_ws;
  // ws: w1a[128K] w1b[128K] w1c[128K] M[9.44MB]
  unsigned short* w1a = (unsigned short*)(ws);
  unsigned short* w1b = (unsigned short*)(ws + 131072);
  unsigned short* w1c = (unsigned short*)(ws + 262144);
  float* Mbuf = (float*)(ws + 393216);

  hipLaunchKernelGGL(prep_kernel, dim3(256), dim3(256), 0, stream, W1, w1a, w1b, w1c);
  hipLaunchKernelGGL(mlp_kernel, dim3(NN / 64), dim3(256), 0, stream,
                     bb, b1, b2, W2, w1a, w1b, w1c, Mbuf);
  hipLaunchKernelGGL(procrustes_kernel, dim3(NN / 256), dim3(256), 0, stream, Mbuf, out);
}